// Round 7
// baseline (410.261 us; speedup 1.0000x reference)
//
#include <hip/hip_runtime.h>
#include <math.h>

// VQVAE graph-transformer forward, fp32 throughout.
// B=4 N=128 DIM=256 HEADS=8 DH=64 EDGE=64 DEPTH=2 K=512 INNER=512
// ekv never materialized. R7: gate+LN folded into GEMM prologues (ping-pong
// nodes buffers), final gate folded into vq. 14 dispatches.

#define DEV __device__ __forceinline__

constexpr int Bn = 4, Nn = 128, DIMn = 256, HEADSn = 8, DHn = 64, EDGEn = 64,
              DEPTHn = 2, Kn = 512, INNERn = 512;
constexpr int QKVW = 1536;
constexpr int PART = 131072;  // stride of partial buffers (floats)

DEV float wave_reduce_sum(float v) {
#pragma unroll
  for (int m = 32; m >= 1; m >>= 1) v += __shfl_xor(v, m);
  return v;
}

DEV float block_reduce_sum_256(float v, float* red) {
  v = wave_reduce_sum(v);
  int tid = threadIdx.x;
  if ((tid & 63) == 0) red[tid >> 6] = v;
  __syncthreads();
  v = red[0] + red[1] + red[2] + red[3];
  __syncthreads();
  return v;
}

DEV float gelu_exact(float x) {
  return 0.5f * x * (1.f + erff(x * 0.70710678118654752f));
}

DEV float dot4(float4 a, float4 b) {
  return a.x * b.x + a.y * b.y + a.z * b.z + a.w * b.w;
}

// ---------------------------------------------------------------------------
// Edge LayerNorm -> e[b][i][c][j]  AND  eT[b][i][j][c]. Block per (b,i).
__global__ __launch_bounds__(128) void edge_ln_kernel(
    const float* __restrict__ edges, const float* __restrict__ g,
    const float* __restrict__ bta, float* __restrict__ e,
    float* __restrict__ eT) {
  __shared__ float ets[128 * 65];
  int blk = blockIdx.x;
  int i = blk & 127, b = blk >> 7;
  int j = threadIdx.x;
  const float* src = edges + (size_t)b * EDGEn * Nn * Nn + i * Nn + j;
  float vals[EDGEn];
  float s = 0.f;
#pragma unroll
  for (int c = 0; c < EDGEn; ++c) {
    float x = src[(size_t)c * (Nn * Nn)];
    vals[c] = x;
    s += x;
  }
  float m = s * (1.0f / 64.0f);
  float s2 = 0.f;
#pragma unroll
  for (int c = 0; c < EDGEn; ++c) {
    float d = vals[c] - m;
    s2 += d * d;
  }
  float inv = 1.f / sqrtf(s2 * (1.0f / 64.0f) + 1e-5f);
  float* dst = e + ((size_t)(b * Nn + i) * EDGEn) * Nn + j;
#pragma unroll
  for (int c = 0; c < EDGEn; ++c) {
    float o = (vals[c] - m) * inv * g[c] + bta[c];
    dst[(size_t)c * Nn] = o;
    ets[j * 65 + c] = o;
  }
  __syncthreads();
  float* dstT = eT + ((size_t)(b * Nn + i) * Nn) * EDGEn;
#pragma unroll
  for (int it = 0; it < 16; ++it) {
    int f4 = it * 128 + j;
    int jj = f4 >> 4, c4 = (f4 & 15) << 2;
    float4 o4 = {ets[jj * 65 + c4], ets[jj * 65 + c4 + 1],
                 ets[jj * 65 + c4 + 2], ets[jj * 65 + c4 + 3]};
    *(float4*)(dstT + (size_t)jj * EDGEn + c4) = o4;
  }
}

// ---------------------------------------------------------------------------
__global__ void rope_table_kernel(float* __restrict__ cost,
                                  float* __restrict__ sint) {
  int t = blockIdx.x * 256 + threadIdx.x;
  if (t >= Nn * 32) return;
  int n = t >> 5, p = t & 31;
  float inv = powf(10000.f, -(float)(2 * p) / 64.f);
  float fr = (float)n * inv;
  cost[t] = cosf(fr);
  sint[t] = sinf(fr);
}

// ---------------------------------------------------------------------------
// Fold kernel: W2[l][h*64+c][n] = sum_d wek[l][c][h64+d] * w_out[l][h64+d][n]
// and b_out2[l][n] = b_out[l][n] + sum_k bek[l][k]*w_out[l][k][n].
__global__ __launch_bounds__(256) void wfold_kernel(
    const float* __restrict__ wek, const float* __restrict__ w_out,
    const float* __restrict__ bek, const float* __restrict__ b_out,
    float* __restrict__ W2, float* __restrict__ b_out2) {
  int blk = blockIdx.x;
  int tid = threadIdx.x;
  if (blk < 64) {
    int l = blk >> 5, h = (blk >> 2) & 7, nt = blk & 3;
    __shared__ float As[64 * 65];
    __shared__ float Bs[64 * 68];
    const float* wekl = wek + (size_t)l * 64 * 512 + h * 64;
    const float* woutl =
        w_out + (size_t)l * 512 * 256 + (size_t)(h * 64) * 256 + nt * 64;
    for (int f = tid; f < 1024; f += 256) {
      int c = f >> 4, d4 = (f & 15) << 2;
      float4 w4 = *(const float4*)(wekl + (size_t)c * 512 + d4);
      As[c * 65 + d4 + 0] = w4.x;
      As[c * 65 + d4 + 1] = w4.y;
      As[c * 65 + d4 + 2] = w4.z;
      As[c * 65 + d4 + 3] = w4.w;
    }
    for (int f = tid; f < 1024; f += 256) {
      int d = f >> 4, n4 = (f & 15) << 2;
      float4 w4 = *(const float4*)(woutl + (size_t)d * 256 + n4);
      Bs[d * 68 + n4 + 0] = w4.x;
      Bs[d * 68 + n4 + 1] = w4.y;
      Bs[d * 68 + n4 + 2] = w4.z;
      Bs[d * 68 + n4 + 3] = w4.w;
    }
    __syncthreads();
    int tx = tid & 15, ty = tid >> 4;
    float acc[4][4] = {};
    for (int d = 0; d < 64; ++d) {
      float4 bv = *(const float4*)&Bs[d * 68 + tx * 4];
#pragma unroll
      for (int u = 0; u < 4; ++u) {
        float a = As[(ty * 4 + u) * 65 + d];
        acc[u][0] += a * bv.x;
        acc[u][1] += a * bv.y;
        acc[u][2] += a * bv.z;
        acc[u][3] += a * bv.w;
      }
    }
#pragma unroll
    for (int u = 0; u < 4; ++u) {
      float4 o = {acc[u][0], acc[u][1], acc[u][2], acc[u][3]};
      *(float4*)(W2 + (size_t)l * 512 * 256 +
                 (size_t)(h * 64 + ty * 4 + u) * 256 + nt * 64 + tx * 4) = o;
    }
  } else {
    int t = blk - 64;
    int l = t >> 2, nt = t & 3;
    __shared__ float part[256];
    int nn = tid & 63, kq = tid >> 6;
    const float* wcol = w_out + (size_t)l * 512 * 256 + nt * 64 + nn;
    float acc = 0.f;
    for (int k = kq * 128; k < kq * 128 + 128; ++k)
      acc += bek[l * 512 + k] * wcol[(size_t)k * 256];
    part[tid] = acc;
    __syncthreads();
    if (tid < 64)
      b_out2[l * 256 + nt * 64 + nn] =
          b_out[l * 256 + nt * 64 + nn] + part[nn] + part[64 + nn] +
          part[128 + nn] + part[192 + nn];
  }
}

// ---------------------------------------------------------------------------
// fp32 GEMM, 32x64 tile, BK=32, 2x4 microtile, register double-buffered B.
// aprep: 0 = A from global (A [+A2] [gelu if aact]); 1 = A = LN(nodesrc);
//        2 = A = LN(gate(sum partials + badd, nodesrc)), write nodesdst.
// Dual-N (W2n at col>=N1), dual-K (k>=Ksplit reads Wkb), split-K via z.
// act: 0 none, 1 exact gelu, 4 qkv mode (rope cols<1024; k section -> kT).
__global__ __launch_bounds__(256) void gemm_kernel(
    const float* __restrict__ A, const float* __restrict__ A2, int aact,
    int aprep, const float* __restrict__ pbuf, int nparts,
    const float* __restrict__ badd, const float* __restrict__ nodesrc,
    float* __restrict__ nodesdst, const float* __restrict__ gw,
    const float* __restrict__ lng, const float* __restrict__ lnb,
    const float* __restrict__ W1, int N1, const float* __restrict__ b1,
    const float* __restrict__ W2n, int N2, const float* __restrict__ b2,
    const float* __restrict__ Wkb, int Ksplit, float* __restrict__ C, int M,
    int Ntot, int K, int kspan, int act, const float* __restrict__ cost,
    const float* __restrict__ sint, float* __restrict__ kT) {
  __shared__ float As[32][34];
  __shared__ __align__(16) float Bs[32][68];
  __shared__ __align__(16) float nvs[32][264];  // LN'd A tile (aprep modes)
  __shared__ float red2[32][10];
  int tid = threadIdx.x;
  int bx = blockIdx.x, by = blockIdx.y, zid = blockIdx.z;
  int tx = tid & 15, ty = tid >> 4;
  int arow = tid >> 3, acol = (tid & 7) << 2;
  int brow = tid >> 4, bcol = (tid & 15) << 2;
  int col0 = bx * 64;
  const float* W = W1;
  const float* bias = b1;
  int Nw = N1, wcol = col0;
  if (W2n && col0 >= N1) {
    W = W2n;
    bias = b2;
    Nw = N2;
    wcol = col0 - N1;
  }
  int kb = zid * kspan, kend = kb + kspan;

  // ---- prologue: build LN'd A-tile in nvs (aprep 1/2) ----
  if (aprep) {
    int pr = tid >> 3, ps = tid & 7;  // row 0..31, seg 0..7 (32 cols each)
    int grow = by * 32 + pr;
    float4 nv[8];
    if (aprep == 2) {
      float4 xv[8], rv[8];
      float pv = 0.f;
#pragma unroll
      for (int i = 0; i < 8; ++i) {
        int c = i * 32 + ps * 4;
        const float* pb = pbuf + (size_t)grow * 256 + c;
        float4 x = *(const float4*)pb;
        for (int p = 1; p < nparts; ++p) {
          float4 t4 = *(const float4*)(pb + (size_t)p * PART);
          x.x += t4.x;
          x.y += t4.y;
          x.z += t4.z;
          x.w += t4.w;
        }
        if (badd) {
          float4 t4 = *(const float4*)(badd + c);
          x.x += t4.x;
          x.y += t4.y;
          x.z += t4.z;
          x.w += t4.w;
        }
        float4 r4 = *(const float4*)(nodesrc + (size_t)grow * 256 + c);
        xv[i] = x;
        rv[i] = r4;
        float4 g0 = *(const float4*)(gw + c);
        float4 g1 = *(const float4*)(gw + 256 + c);
        float4 g2 = *(const float4*)(gw + 512 + c);
        float4 dx = {x.x - r4.x, x.y - r4.y, x.z - r4.z, x.w - r4.w};
        pv += dot4(x, g0) + dot4(r4, g1) + dot4(dx, g2);
      }
      red2[pr][ps] = pv;
      __syncthreads();
      float ssum = 0.f;
#pragma unroll
      for (int s = 0; s < 8; ++s) ssum += red2[pr][s];
      float gsig = 1.f / (1.f + expf(-ssum));
      float mp = 0.f;
#pragma unroll
      for (int i = 0; i < 8; ++i) {
        float4 x = xv[i], r4 = rv[i];
        float4 n4 = {x.x * gsig + r4.x * (1.f - gsig),
                     x.y * gsig + r4.y * (1.f - gsig),
                     x.z * gsig + r4.z * (1.f - gsig),
                     x.w * gsig + r4.w * (1.f - gsig)};
        nv[i] = n4;
        mp += n4.x + n4.y + n4.z + n4.w;
        int c = i * 32 + ps * 4;
        *(float4*)(nodesdst + (size_t)grow * 256 + c) = n4;
      }
      __syncthreads();
      red2[pr][ps] = mp;
      __syncthreads();
      // fallthrough to LN below with nv[] populated
      float msum = 0.f;
#pragma unroll
      for (int s = 0; s < 8; ++s) msum += red2[pr][s];
      float mean = msum * (1.0f / 256.0f);
      float vp = 0.f;
#pragma unroll
      for (int i = 0; i < 8; ++i) {
        float4 n4 = nv[i];
        float d0 = n4.x - mean, d1 = n4.y - mean, d2 = n4.z - mean,
              d3 = n4.w - mean;
        vp += d0 * d0 + d1 * d1 + d2 * d2 + d3 * d3;
      }
      __syncthreads();
      red2[pr][ps] = vp;
      __syncthreads();
      float vsum = 0.f;
#pragma unroll
      for (int s = 0; s < 8; ++s) vsum += red2[pr][s];
      float inv = 1.f / sqrtf(vsum * (1.0f / 256.0f) + 1e-5f);
#pragma unroll
      for (int i = 0; i < 8; ++i) {
        int c = i * 32 + ps * 4;
        float4 lg = *(const float4*)(lng + c);
        float4 lb = *(const float4*)(lnb + c);
        float4 n4 = nv[i];
        float4 o4 = {(n4.x - mean) * inv * lg.x + lb.x,
                     (n4.y - mean) * inv * lg.y + lb.y,
                     (n4.z - mean) * inv * lg.z + lb.z,
                     (n4.w - mean) * inv * lg.w + lb.w};
        *(float4*)&nvs[pr][c] = o4;
      }
    } else {  // aprep == 1: plain LN of nodesrc
      float mp = 0.f;
#pragma unroll
      for (int i = 0; i < 8; ++i) {
        int c = i * 32 + ps * 4;
        float4 r4 = *(const float4*)(nodesrc + (size_t)grow * 256 + c);
        nv[i] = r4;
        mp += r4.x + r4.y + r4.z + r4.w;
      }
      red2[pr][ps] = mp;
      __syncthreads();
      float msum = 0.f;
#pragma unroll
      for (int s = 0; s < 8; ++s) msum += red2[pr][s];
      float mean = msum * (1.0f / 256.0f);
      float vp = 0.f;
#pragma unroll
      for (int i = 0; i < 8; ++i) {
        float4 n4 = nv[i];
        float d0 = n4.x - mean, d1 = n4.y - mean, d2 = n4.z - mean,
              d3 = n4.w - mean;
        vp += d0 * d0 + d1 * d1 + d2 * d2 + d3 * d3;
      }
      __syncthreads();
      red2[pr][ps] = vp;
      __syncthreads();
      float vsum = 0.f;
#pragma unroll
      for (int s = 0; s < 8; ++s) vsum += red2[pr][s];
      float inv = 1.f / sqrtf(vsum * (1.0f / 256.0f) + 1e-5f);
#pragma unroll
      for (int i = 0; i < 8; ++i) {
        int c = i * 32 + ps * 4;
        float4 lg = *(const float4*)(lng + c);
        float4 lb = *(const float4*)(lnb + c);
        float4 n4 = nv[i];
        float4 o4 = {(n4.x - mean) * inv * lg.x + lb.x,
                     (n4.y - mean) * inv * lg.y + lb.y,
                     (n4.z - mean) * inv * lg.z + lb.z,
                     (n4.w - mean) * inv * lg.w + lb.w};
        *(float4*)&nvs[pr][c] = o4;
      }
    }
    __syncthreads();
  }

  const float* arp = A ? A + (size_t)(by * 32 + arow) * K : nullptr;
  const float* arp2 = A2 ? A2 + (size_t)(by * 32 + arow) * K : nullptr;
  auto load_a = [&](int kpos) -> float4 {
    float4 a = *(const float4*)(arp + kpos + acol);
    if (arp2) {
      float4 a2 = *(const float4*)(arp2 + kpos + acol);
      a.x += a2.x;
      a.y += a2.y;
      a.z += a2.z;
      a.w += a2.w;
    }
    if (aact == 1) {
      a.x = gelu_exact(a.x);
      a.y = gelu_exact(a.y);
      a.z = gelu_exact(a.z);
      a.w = gelu_exact(a.w);
    }
    return a;
  };

  float4 a_nxt;
  if (!aprep) a_nxt = load_a(kb);
  const float* w0p;
  const float* w1p;
  {
    int kr0 = kb + brow, kr1 = kb + brow + 16;
    w0p = (Ksplit && kr0 >= Ksplit)
              ? Wkb + (size_t)(kr0 - Ksplit) * Nw + wcol + bcol
              : W + (size_t)kr0 * Nw + wcol + bcol;
    w1p = (Ksplit && kr1 >= Ksplit)
              ? Wkb + (size_t)(kr1 - Ksplit) * Nw + wcol + bcol
              : W + (size_t)kr1 * Nw + wcol + bcol;
  }
  float4 b0_nxt = *(const float4*)w0p;
  float4 b1_nxt = *(const float4*)w1p;

  float acc[2][4] = {};
  for (int k0 = kb; k0 < kend; k0 += 32) {
    float4 a4 = aprep ? *(const float4*)&nvs[arow][k0 + acol] : a_nxt;
    As[acol + 0][arow] = a4.x;
    As[acol + 1][arow] = a4.y;
    As[acol + 2][arow] = a4.z;
    As[acol + 3][arow] = a4.w;
    *(float4*)&Bs[brow][bcol] = b0_nxt;
    *(float4*)&Bs[brow + 16][bcol] = b1_nxt;
    __syncthreads();
    int kn = k0 + 32;
    if (kn < kend) {
      if (!aprep) a_nxt = load_a(kn);
      int kr0 = kn + brow, kr1 = kn + brow + 16;
      w0p = (Ksplit && kr0 >= Ksplit)
                ? Wkb + (size_t)(kr0 - Ksplit) * Nw + wcol + bcol
                : W + (size_t)kr0 * Nw + wcol + bcol;
      w1p = (Ksplit && kr1 >= Ksplit)
                ? Wkb + (size_t)(kr1 - Ksplit) * Nw + wcol + bcol
                : W + (size_t)kr1 * Nw + wcol + bcol;
      b0_nxt = *(const float4*)w0p;
      b1_nxt = *(const float4*)w1p;
    }
#pragma unroll
    for (int kk = 0; kk < 32; ++kk) {
      float2 av = *(const float2*)&As[kk][ty * 2];
      float4 bv = *(const float4*)&Bs[kk][tx * 4];
      acc[0][0] += av.x * bv.x;
      acc[0][1] += av.x * bv.y;
      acc[0][2] += av.x * bv.z;
      acc[0][3] += av.x * bv.w;
      acc[1][0] += av.y * bv.x;
      acc[1][1] += av.y * bv.y;
      acc[1][2] += av.y * bv.z;
      acc[1][3] += av.y * bv.w;
    }
    __syncthreads();
  }
  int ccol = wcol + tx * 4;
  bool ksec = (act == 4) && (col0 >= 512) && (col0 < 1024);
  float* trans = (float*)Bs;
  float* Cz = C + (size_t)zid * M * Ntot;
#pragma unroll
  for (int u = 0; u < 2; ++u) {
    int r = by * 32 + ty * 2 + u;
    float o[4];
#pragma unroll
    for (int w = 0; w < 4; ++w)
      o[w] = acc[u][w] + (zid == 0 ? bias[ccol + w] : 0.f);
    if (act == 1) {
#pragma unroll
      for (int w = 0; w < 4; ++w) o[w] = gelu_exact(o[w]);
    } else if (act == 4 && col0 < 1024) {
      int n = r & 127;
      int p0 = (ccol & 63) >> 1;
      float c0 = cost[n * 32 + p0], s0 = sint[n * 32 + p0];
      float c1 = cost[n * 32 + p0 + 1], s1 = sint[n * 32 + p0 + 1];
      float x0 = o[0], x1 = o[1], x2 = o[2], x3 = o[3];
      o[0] = x0 * c0 - x1 * s0;
      o[1] = x1 * c0 + x0 * s0;
      o[2] = x2 * c1 - x3 * s1;
      o[3] = x3 * c1 + x2 * s1;
    }
    if (ksec) {
      int jl = ty * 2 + u;
#pragma unroll
      for (int w = 0; w < 4; ++w) trans[(tx * 4 + w) * 33 + jl] = o[w];
    } else {
      float4 o4 = {o[0], o[1], o[2], o[3]};
      *(float4*)(Cz + (size_t)r * Ntot + col0 + tx * 4) = o4;
    }
  }
  if (ksec) {
    __syncthreads();
    int h = (col0 - 512) >> 6;
    int bb = (by * 32) >> 7;
#pragma unroll
    for (int q = 0; q < 2; ++q) {
      int f4 = tid * 2 + q;
      int dl = f4 >> 3, j4 = (f4 & 7) << 2;
      int jj = (by * 32 + j4) & 127;
      float4 o4 = {trans[dl * 33 + j4], trans[dl * 33 + j4 + 1],
                   trans[dl * 33 + j4 + 2], trans[dl * 33 + j4 + 3]};
      *(float4*)(kT + ((size_t)(bb * 8 + h) * 64 + dl) * 128 + jj) = o4;
    }
  }
}

// ---------------------------------------------------------------------------
// Attention + qe + out-proj partial. Block per (b,h,i-quad), 128 threads.
__global__ __launch_bounds__(128) void attn_kernel(
    const float* __restrict__ qkv, const float* __restrict__ e,
    const float* __restrict__ eT, const float* __restrict__ kT,
    const float* __restrict__ wek, const float* __restrict__ w_out,
    const float* __restrict__ W2, float* __restrict__ proj) {
  __shared__ __align__(16) float qs[256];
  __shared__ __align__(16) float qes[256];
  __shared__ __align__(16) float att[512];
  __shared__ float avh[512];
  __shared__ float aeh[512];
  __shared__ float wekh[64 * 65];
  int blk = blockIdx.x;
  int iq = blk & 31;
  int bh = blk >> 5;
  int h = bh & 7, b = bh >> 3;
  int i0 = iq * 4;
  int row0 = b * 128 + i0;
  int tid = threadIdx.x;

  for (int f = tid; f < 256; f += 128) {
    int ii = f >> 6, d = f & 63;
    qs[f] = qkv[(size_t)(row0 + ii) * QKVW + h * 64 + d];
  }
  for (int f = tid; f < 4096; f += 128) {
    int c = f >> 6, d = f & 63;
    wekh[c * 65 + d] = wek[(size_t)c * INNERn + h * 64 + d];
  }
  __syncthreads();

  for (int f = tid; f < 256; f += 128) {
    int ii = f >> 6, c = f & 63;
    float acc = 0.f;
#pragma unroll
    for (int d = 0; d < 64; ++d) acc += qs[ii * 64 + d] * wekh[c * 65 + d];
    qes[f] = acc;
  }
  __syncthreads();

  int i2 = tid >> 5, j4 = tid & 31;
  float s0 = 0.f, s1 = 0.f, s2 = 0.f, s3 = 0.f;
  {
    const float* ktb = kT + ((size_t)bh * 64) * 128 + j4 * 4;
#pragma unroll
    for (int d4 = 0; d4 < 64; d4 += 4) {
      float4 q4 = *(const float4*)&qs[i2 * 64 + d4];
      float4 k0 = *(const float4*)(ktb + (size_t)(d4 + 0) * 128);
      float4 k1 = *(const float4*)(ktb + (size_t)(d4 + 1) * 128);
      float4 k2 = *(const float4*)(ktb + (size_t)(d4 + 2) * 128);
      float4 k3 = *(const float4*)(ktb + (size_t)(d4 + 3) * 128);
      s0 += q4.x * k0.x + q4.y * k1.x + q4.z * k2.x + q4.w * k3.x;
      s1 += q4.x * k0.y + q4.y * k1.y + q4.z * k2.y + q4.w * k3.y;
      s2 += q4.x * k0.z + q4.y * k1.z + q4.z * k2.z + q4.w * k3.z;
      s3 += q4.x * k0.w + q4.y * k1.w + q4.z * k2.w + q4.w * k3.w;
    }
    const float* eb = e + ((size_t)(row0 + i2) * 64) * 128 + j4 * 4;
#pragma unroll
    for (int c4 = 0; c4 < 64; c4 += 4) {
      float4 qe4 = *(const float4*)&qes[i2 * 64 + c4];
      float4 e0 = *(const float4*)(eb + (size_t)(c4 + 0) * 128);
      float4 e1 = *(const float4*)(eb + (size_t)(c4 + 1) * 128);
      float4 e2 = *(const float4*)(eb + (size_t)(c4 + 2) * 128);
      float4 e3 = *(const float4*)(eb + (size_t)(c4 + 3) * 128);
      s0 += qe4.x * e0.x + qe4.y * e1.x + qe4.z * e2.x + qe4.w * e3.x;
      s1 += qe4.x * e0.y + qe4.y * e1.y + qe4.z * e2.y + qe4.w * e3.y;
      s2 += qe4.x * e0.z + qe4.y * e1.z + qe4.z * e2.z + qe4.w * e3.z;
      s3 += qe4.x * e0.w + qe4.y * e1.w + qe4.z * e2.w + qe4.w * e3.w;
    }
    s0 *= 0.125f;
    s1 *= 0.125f;
    s2 *= 0.125f;
    s3 *= 0.125f;
  }
  {
    float mx = fmaxf(fmaxf(s0, s1), fmaxf(s2, s3));
#pragma unroll
    for (int m = 16; m >= 1; m >>= 1) mx = fmaxf(mx, __shfl_xor(mx, m));
    float p0 = expf(s0 - mx), p1 = expf(s1 - mx), p2 = expf(s2 - mx),
          p3 = expf(s3 - mx);
    float sm = p0 + p1 + p2 + p3;
#pragma unroll
    for (int m = 16; m >= 1; m >>= 1) sm += __shfl_xor(sm, m);
    float inv = 1.f / sm;
    float4 a4 = {p0 * inv, p1 * inv, p2 * inv, p3 * inv};
    *(float4*)&att[i2 * 128 + j4 * 4] = a4;
  }
  __syncthreads();

  {
    int d = tid & 63, half = tid >> 6;
    float av0 = 0.f, av1 = 0.f, av2 = 0.f, av3 = 0.f;
    float ae0 = 0.f, ae1 = 0.f, ae2 = 0.f, ae3 = 0.f;
    const float* vb = qkv + (size_t)(b * 128) * QKVW + 1024 + h * 64 + d;
    const float* etb = eT + ((size_t)row0 * 128) * 64 + d;
    for (int jq = 0; jq < 16; ++jq) {
      int jb = half * 64 + jq * 4;
      float4 a0 = *(const float4*)&att[0 * 128 + jb];
      float4 a1 = *(const float4*)&att[1 * 128 + jb];
      float4 a2 = *(const float4*)&att[2 * 128 + jb];
      float4 a3 = *(const float4*)&att[3 * 128 + jb];
#pragma unroll
      for (int t = 0; t < 4; ++t) {
        int j = jb + t;
        float vv = vb[(size_t)j * QKVW];
        float at0 = ((const float*)&a0)[t];
        float at1 = ((const float*)&a1)[t];
        float at2 = ((const float*)&a2)[t];
        float at3 = ((const float*)&a3)[t];
        av0 += at0 * vv;
        av1 += at1 * vv;
        av2 += at2 * vv;
        av3 += at3 * vv;
        float e0 = etb[(size_t)j * 64];
        float e1 = etb[8192 + (size_t)j * 64];
        float e2 = etb[16384 + (size_t)j * 64];
        float e3 = etb[24576 + (size_t)j * 64];
        ae0 += at0 * e0;
        ae1 += at1 * e1;
        ae2 += at2 * e2;
        ae3 += at3 * e3;
      }
    }
    avh[half * 256 + 0 * 64 + d] = av0;
    avh[half * 256 + 1 * 64 + d] = av1;
    avh[half * 256 + 2 * 64 + d] = av2;
    avh[half * 256 + 3 * 64 + d] = av3;
    aeh[half * 256 + 0 * 64 + d] = ae0;
    aeh[half * 256 + 1 * 64 + d] = ae1;
    aeh[half * 256 + 2 * 64 + d] = ae2;
    aeh[half * 256 + 3 * 64 + d] = ae3;
  }
  __syncthreads();

  for (int f = tid; f < 256; f += 128) {
    int ii = f >> 6, dd = f & 63;
    att[ii * 128 + dd] = avh[ii * 64 + dd] + avh[256 + ii * 64 + dd];
    att[ii * 128 + 64 + dd] = aeh[ii * 64 + dd] + aeh[256 + ii * 64 + dd];
  }
  __syncthreads();

  {
    int rp = tid >> 6, n4 = (tid & 63) << 2;
    int r0 = rp * 2, r1 = rp * 2 + 1;
    float o0[4] = {}, o1[4] = {};
    const float* wo = w_out + (size_t)(h * 64) * 256 + n4;
#pragma unroll 8
    for (int k = 0; k < 64; ++k) {
      float4 w4 = *(const float4*)(wo + (size_t)k * 256);
      float a0 = att[r0 * 128 + k];
      float a1 = att[r1 * 128 + k];
      o0[0] += a0 * w4.x;
      o0[1] += a0 * w4.y;
      o0[2] += a0 * w4.z;
      o0[3] += a0 * w4.w;
      o1[0] += a1 * w4.x;
      o1[1] += a1 * w4.y;
      o1[2] += a1 * w4.z;
      o1[3] += a1 * w4.w;
    }
    const float* w2 = W2 + (size_t)(h * 64) * 256 + n4;
#pragma unroll 8
    for (int k = 0; k < 64; ++k) {
      float4 w4 = *(const float4*)(w2 + (size_t)k * 256);
      float a0 = att[r0 * 128 + 64 + k];
      float a1 = att[r1 * 128 + 64 + k];
      o0[0] += a0 * w4.x;
      o0[1] += a0 * w4.y;
      o0[2] += a0 * w4.z;
      o0[3] += a0 * w4.w;
      o1[0] += a1 * w4.x;
      o1[1] += a1 * w4.y;
      o1[2] += a1 * w4.z;
      o1[3] += a1 * w4.w;
    }
    float* pp = proj + (size_t)h * PART;
    float4 v0 = {o0[0], o0[1], o0[2], o0[3]};
    float4 v1 = {o1[0], o1[1], o1[2], o1[3]};
    *(float4*)(pp + (size_t)(row0 + r0) * 256 + n4) = v0;
    *(float4*)(pp + (size_t)(row0 + r1) * 256 + n4) = v1;
  }
}

// ---------------------------------------------------------------------------
// VQ nearest neighbor with fused final gate: z = gate(sum 4 partials, nodesrc).
__global__ __launch_bounds__(256) void vq_kernel(
    const float* __restrict__ pbuf, const float* __restrict__ nodesrc,
    const float* __restrict__ gw, const float* __restrict__ codebook,
    float* __restrict__ out) {
  __shared__ __align__(16) float zs[4 * 256];
  __shared__ float red[4];
  __shared__ float wval[4][4];
  __shared__ int widx[4][4];
  __shared__ int fidx[4];
  int row0 = blockIdx.x * 4;
  int tid = threadIdx.x;
  // gate prologue: 4 rows
  for (int r = 0; r < 4; ++r) {
    size_t off = (size_t)(row0 + r) * DIMn + tid;
    float xv = pbuf[off] + pbuf[off + PART] + pbuf[off + 2 * PART] +
               pbuf[off + 3 * PART];
    float rv = nodesrc[off];
    float pv =
        xv * gw[tid] + rv * gw[DIMn + tid] + (xv - rv) * gw[2 * DIMn + tid];
    float ssum = block_reduce_sum_256(pv, red);
    float gsig = 1.f / (1.f + expf(-ssum));
    zs[r * 256 + tid] = xv * gsig + rv * (1.f - gsig);
  }
  __syncthreads();
  int k1 = tid, k2 = tid + 256;
  const float4* c1p = (const float4*)(codebook + (size_t)k1 * DIMn);
  const float4* c2p = (const float4*)(codebook + (size_t)k2 * DIMn);
  float dot[4][2] = {};
  float cc0 = 0.f, cc1 = 0.f;
#pragma unroll 8
  for (int d4 = 0; d4 < 64; ++d4) {
    float4 c1 = c1p[d4], c2 = c2p[d4];
    cc0 += c1.x * c1.x + c1.y * c1.y + c1.z * c1.z + c1.w * c1.w;
    cc1 += c2.x * c2.x + c2.y * c2.y + c2.z * c2.z + c2.w * c2.w;
#pragma unroll
    for (int r = 0; r < 4; ++r) {
      float4 z = *(const float4*)&zs[r * 256 + d4 * 4];
      dot[r][0] += c1.x * z.x + c1.y * z.y + c1.z * z.z + c1.w * z.w;
      dot[r][1] += c2.x * z.x + c2.y * z.y + c2.z * z.z + c2.w * z.w;
    }
  }
  int lane = tid & 63, w = tid >> 6;
#pragma unroll
  for (int r = 0; r < 4; ++r) {
    float bv = cc0 - 2.f * dot[r][0];
    int bi = k1;
    float v2 = cc1 - 2.f * dot[r][1];
    if (v2 < bv) {
      bv = v2;
      bi = k2;
    }
#pragma unroll
    for (int m = 32; m >= 1; m >>= 1) {
      float ov = __shfl_xor(bv, m);
      int oi = __shfl_xor(bi, m);
      if (ov < bv || (ov == bv && oi < bi)) {
        bv = ov;
        bi = oi;
      }
    }
    if (lane == 0) {
      wval[r][w] = bv;
      widx[r][w] = bi;
    }
  }
  __syncthreads();
  if (tid < 4) {
    float bb = wval[tid][0];
    int bi = widx[tid][0];
    for (int t = 1; t < 4; ++t)
      if (wval[tid][t] < bb || (wval[tid][t] == bb && widx[tid][t] < bi)) {
        bb = wval[tid][t];
        bi = widx[tid][t];
      }
    fidx[tid] = bi;
  }
  __syncthreads();
  for (int f = tid; f < 1024; f += 256) {
    int r = f >> 8, d = f & 255;
    float zv = zs[f];
    float zq = codebook[(size_t)fidx[r] * DIMn + d];
    out[(size_t)(row0 + r) * DIMn + d] = zv + (zq - zv);
  }
}

// ---------------------------------------------------------------------------
extern "C" void kernel_launch(void* const* d_in, const int* in_sizes, int n_in,
                              void* d_out, int out_size, void* d_ws,
                              size_t ws_size, hipStream_t stream) {
  const float* nodes_in = (const float*)d_in[0];
  const float* edges = (const float*)d_in[1];
  const float* edge_ln_g = (const float*)d_in[2];
  const float* edge_ln_b = (const float*)d_in[3];
  const float* ln1_g = (const float*)d_in[4];
  const float* ln1_b = (const float*)d_in[5];
  const float* w_exp = (const float*)d_in[6];
  const float* b_exp = (const float*)d_in[7];
  const float* w_q = (const float*)d_in[8];
  const float* b_q = (const float*)d_in[9];
  const float* w_kv = (const float*)d_in[10];
  const float* b_kv = (const float*)d_in[11];
  const float* w_ekv = (const float*)d_in[12];
  const float* b_ekv = (const float*)d_in[13];
  const float* w_out = (const float*)d_in[14];
  const float* b_out = (const float*)d_in[15];
  const float* gate1_w = (const float*)d_in[16];
  const float* ln2_g = (const float*)d_in[17];
  const float* ln2_b = (const float*)d_in[18];
  const float* w_ff1 = (const float*)d_in[19];
  const float* b_ff1 = (const float*)d_in[20];
  const float* w_ff2 = (const float*)d_in[21];
  const float* b_ff2 = (const float*)d_in[22];
  const float* gate2_w = (const float*)d_in[23];
  const float* codebook = (const float*)d_in[24];

  float* ws = (float*)d_ws;
  float* e_buf = ws;                  // 4194304
  float* eT_buf = e_buf + 4194304;    // 4194304
  float* cost = eT_buf + 4194304;     // 4096
  float* sint = cost + 4096;          // 4096
  float* nA = sint + 4096;            // 131072
  float* nB = nA + 131072;            // 131072
  float* nC = nB + 131072;            // 131072
  float* xe = nC + 131072;            // 524288 (2 split-K partials)
  float* qkvb = xe + 524288;          // 786432
  float* kTb = qkvb + 786432;         // 262144
  float* proj = kTb + 262144;         // 1048576 (8 per-head / 4 splitK parts)
  float* ff1 = proj + 1048576;        // 1048576 (2 split-K partials)
  float* W2buf = ff1 + 1048576;       // 262144
  float* bout2 = W2buf + 262144;      // 512

  wfold_kernel<<<72, 256, 0, stream>>>(w_ekv, w_out, b_ekv, b_out, W2buf,
                                       bout2);
  edge_ln_kernel<<<512, 128, 0, stream>>>(edges, edge_ln_g, edge_ln_b, e_buf,
                                          eT_buf);
  rope_table_kernel<<<16, 256, 0, stream>>>(cost, sint);

  // residual ping-pong: nodes sources per stage
  const float* nsrc[3] = {nodes_in, nA, nB};  // before gate1-L0/gate2-L0/gate1-L1
  float* ndst[3] = {nA, nB, nC};

  for (int l = 0; l < DEPTHn; ++l) {
    // exp GEMM: prologue = (l==0) ? LN1(nodes_in) : gate2(L0)+LN1
    if (l == 0) {
      gemm_kernel<<<dim3(8, 16, 2), 256, 0, stream>>>(
          nullptr, nullptr, 0, 1, nullptr, 0, nullptr, nodes_in, nullptr,
          nullptr, ln1_g, ln1_b, w_exp, 512, b_exp, nullptr, 0, nullptr,
          nullptr, 0, xe, 512, 512, 256, 128, 0, cost, sint, nullptr);
    } else {
      gemm_kernel<<<dim3(8, 16, 2), 256, 0, stream>>>(
          nullptr, nullptr, 0, 2, proj, 4, nullptr, nsrc[1], ndst[1],
          gate2_w, ln1_g + 256, ln1_b + 256, w_exp + 256 * 512, 512,
          b_exp + 512, nullptr, 0, nullptr, nullptr, 0, xe, 512, 512, 256,
          128, 0, cost, sint, nullptr);
    }
    // fused q|kv (A = sum of 2 xe partials), rope epilogue + kT scatter
    gemm_kernel<<<dim3(24, 16, 1), 256, 0, stream>>>(
        xe, xe + 262144, 0, 0, nullptr, 0, nullptr, nullptr, nullptr, nullptr,
        nullptr, nullptr, w_q + l * 512 * 512, 512, b_q + l * 512,
        w_kv + l * 512 * 1024, 1024, b_kv + l * 1024, nullptr, 0, qkvb, 512,
        QKVW, 512, 512, 4, cost, sint, kTb);
    // attention (+qe, +out-proj per-head partials)
    attn_kernel<<<1024, 128, 0, stream>>>(qkvb, e_buf, eT_buf, kTb,
                                          w_ekv + l * 64 * 512,
                                          w_out + l * 512 * 256,
                                          W2buf + l * 512 * 256, proj);
    // ff1: prologue = gate1 + LN2; writes nodes ping-pong
    gemm_kernel<<<dim3(16, 16, 2), 256, 0, stream>>>(
        nullptr, nullptr, 0, 2, proj, 8, bout2 + l * 256, nsrc[l * 2],
        ndst[l * 2], gate1_w + l * 768, ln2_g + l * 256, ln2_b + l * 256,
        w_ff1 + l * 256 * 1024, 1024, b_ff1 + l * 1024, nullptr, 0, nullptr,
        nullptr, 0, ff1, 512, 1024, 256, 128, 0, cost, sint, nullptr);
    // ff2: A = gelu(ff1 p0 + p1), split-K x4 -> proj partials
    gemm_kernel<<<dim3(4, 16, 4), 256, 0, stream>>>(
        ff1, ff1 + 524288, 1, 0, nullptr, 0, nullptr, nullptr, nullptr,
        nullptr, nullptr, nullptr, w_ff2 + l * 1024 * 256, 256,
        b_ff2 + l * 256, nullptr, 0, nullptr, nullptr, 0, proj, 512, 256,
        1024, 256, 0, cost, sint, nullptr);
  }
  // vq with fused final gate2 (layer 1): reads proj(4 parts) + nC
  vq_kernel<<<128, 256, 0, stream>>>(proj, nC, gate2_w + 768, codebook,
                                     (float*)d_out);
}

// Round 8
// 365.849 us; speedup vs baseline: 1.1214x; 1.1214x over previous
//
#include <hip/hip_runtime.h>
#include <math.h>

// VQVAE graph-transformer forward, fp32 throughout.
// B=4 N=128 DIM=256 HEADS=8 DH=64 EDGE=64 DEPTH=2 K=512 INNER=512
// ekv never materialized. R8 = R6 structure (best: 367us) + one-shot setup
// kernels (wfold/edge_ln/rope/ln0) merged into a single prep_kernel.
// 16 dispatches. R7's GEMM-prologue fusion reverted (32x redundant gate+LN
// + 48KB LDS killed occupancy -> 410us).

#define DEV __device__ __forceinline__

constexpr int Bn = 4, Nn = 128, DIMn = 256, HEADSn = 8, DHn = 64, EDGEn = 64,
              DEPTHn = 2, Kn = 512, INNERn = 512;
constexpr int QKVW = 1536;
constexpr int PART = 131072;  // stride of partial buffers (floats)

DEV float wave_reduce_sum(float v) {
#pragma unroll
  for (int m = 32; m >= 1; m >>= 1) v += __shfl_xor(v, m);
  return v;
}

DEV float block_reduce_sum_256(float v, float* red) {
  v = wave_reduce_sum(v);
  int tid = threadIdx.x;
  if ((tid & 63) == 0) red[tid >> 6] = v;
  __syncthreads();
  v = red[0] + red[1] + red[2] + red[3];
  __syncthreads();
  return v;
}

DEV float gelu_exact(float x) {
  return 0.5f * x * (1.f + erff(x * 0.70710678118654752f));
}

// ---------------------------------------------------------------------------
// prep_kernel: all one-shot setup, block-range dispatched. 256 threads.
//  blk 0..63    : wfold W2 tile (l,h,nt)
//  blk 64..71   : wfold b_out2 (l,nt)
//  blk 72..583  : edge LN for (b,i) -> e[b][i][c][j] and eT[b][i][j][c]
//  blk 584..599 : rope tables
//  blk 600..1111: LN0 row (xln + nodes copy)
__global__ __launch_bounds__(256) void prep_kernel(
    const float* __restrict__ edges, const float* __restrict__ eg,
    const float* __restrict__ eb, float* __restrict__ e,
    float* __restrict__ eT, float* __restrict__ cost, float* __restrict__ sint,
    const float* __restrict__ nodes_in, const float* __restrict__ ln1_g,
    const float* __restrict__ ln1_b, float* __restrict__ xln,
    float* __restrict__ nodes, const float* __restrict__ wek,
    const float* __restrict__ w_out, const float* __restrict__ bek,
    const float* __restrict__ b_out, float* __restrict__ W2,
    float* __restrict__ b_out2) {
  __shared__ float smem[8512];  // aliased per role (34 KB)
  int blk = blockIdx.x;
  int tid = threadIdx.x;

  if (blk < 64) {  // ---- wfold W2 ----
    int l = blk >> 5, h = (blk >> 2) & 7, nt = blk & 3;
    float* As = smem;             // 64*65
    float* Bs = smem + 4160;      // 64*68
    const float* wekl = wek + (size_t)l * 64 * 512 + h * 64;
    const float* woutl =
        w_out + (size_t)l * 512 * 256 + (size_t)(h * 64) * 256 + nt * 64;
    for (int f = tid; f < 1024; f += 256) {
      int c = f >> 4, d4 = (f & 15) << 2;
      float4 w4 = *(const float4*)(wekl + (size_t)c * 512 + d4);
      As[c * 65 + d4 + 0] = w4.x;
      As[c * 65 + d4 + 1] = w4.y;
      As[c * 65 + d4 + 2] = w4.z;
      As[c * 65 + d4 + 3] = w4.w;
    }
    for (int f = tid; f < 1024; f += 256) {
      int d = f >> 4, n4 = (f & 15) << 2;
      float4 w4 = *(const float4*)(woutl + (size_t)d * 256 + n4);
      Bs[d * 68 + n4 + 0] = w4.x;
      Bs[d * 68 + n4 + 1] = w4.y;
      Bs[d * 68 + n4 + 2] = w4.z;
      Bs[d * 68 + n4 + 3] = w4.w;
    }
    __syncthreads();
    int tx = tid & 15, ty = tid >> 4;
    float acc[4][4] = {};
    for (int d = 0; d < 64; ++d) {
      float4 bv = *(const float4*)&Bs[d * 68 + tx * 4];
#pragma unroll
      for (int u = 0; u < 4; ++u) {
        float a = As[(ty * 4 + u) * 65 + d];
        acc[u][0] += a * bv.x;
        acc[u][1] += a * bv.y;
        acc[u][2] += a * bv.z;
        acc[u][3] += a * bv.w;
      }
    }
#pragma unroll
    for (int u = 0; u < 4; ++u) {
      float4 o = {acc[u][0], acc[u][1], acc[u][2], acc[u][3]};
      *(float4*)(W2 + (size_t)l * 512 * 256 +
                 (size_t)(h * 64 + ty * 4 + u) * 256 + nt * 64 + tx * 4) = o;
    }
  } else if (blk < 72) {  // ---- wfold b_out2 ----
    int t = blk - 64;
    int l = t >> 2, nt = t & 3;
    float* part = smem;
    int nn = tid & 63, kq = tid >> 6;
    const float* wcol = w_out + (size_t)l * 512 * 256 + nt * 64 + nn;
    float acc = 0.f;
    for (int k = kq * 128; k < kq * 128 + 128; ++k)
      acc += bek[l * 512 + k] * wcol[(size_t)k * 256];
    part[tid] = acc;
    __syncthreads();
    if (tid < 64)
      b_out2[l * 256 + nt * 64 + nn] =
          b_out[l * 256 + nt * 64 + nn] + part[nn] + part[64 + nn] +
          part[128 + nn] + part[192 + nn];
  } else if (blk < 584) {  // ---- edge LN ----
    float* ets = smem;  // 128*65
    int eidx = blk - 72;
    int i = eidx & 127, b = eidx >> 7;
    int j = tid & 127;
    bool act = tid < 128;
    if (act) {
      const float* src = edges + (size_t)b * EDGEn * Nn * Nn + i * Nn + j;
      float vals[EDGEn];
      float s = 0.f;
#pragma unroll
      for (int c = 0; c < EDGEn; ++c) {
        float x = src[(size_t)c * (Nn * Nn)];
        vals[c] = x;
        s += x;
      }
      float m = s * (1.0f / 64.0f);
      float s2 = 0.f;
#pragma unroll
      for (int c = 0; c < EDGEn; ++c) {
        float d = vals[c] - m;
        s2 += d * d;
      }
      float inv = 1.f / sqrtf(s2 * (1.0f / 64.0f) + 1e-5f);
      float* dst = e + ((size_t)(b * Nn + i) * EDGEn) * Nn + j;
#pragma unroll
      for (int c = 0; c < EDGEn; ++c) {
        float o = (vals[c] - m) * inv * eg[c] + eb[c];
        dst[(size_t)c * Nn] = o;
        ets[j * 65 + c] = o;
      }
    }
    __syncthreads();
    if (act) {
      float* dstT = eT + ((size_t)(b * Nn + i) * Nn) * EDGEn;
#pragma unroll
      for (int it = 0; it < 16; ++it) {
        int f4 = it * 128 + j;
        int jj = f4 >> 4, c4 = (f4 & 15) << 2;
        float4 o4 = {ets[jj * 65 + c4], ets[jj * 65 + c4 + 1],
                     ets[jj * 65 + c4 + 2], ets[jj * 65 + c4 + 3]};
        *(float4*)(dstT + (size_t)jj * EDGEn + c4) = o4;
      }
    }
  } else if (blk < 600) {  // ---- rope tables ----
    int t = (blk - 584) * 256 + tid;
    if (t < Nn * 32) {
      int n = t >> 5, p = t & 31;
      float inv = powf(10000.f, -(float)(2 * p) / 64.f);
      float fr = (float)n * inv;
      cost[t] = cosf(fr);
      sint[t] = sinf(fr);
    }
  } else {  // ---- LN0 + nodes copy ----
    float* red = smem;
    int row = blk - 600;
    float v = nodes_in[(size_t)row * DIMn + tid];
    nodes[(size_t)row * DIMn + tid] = v;
    float m = block_reduce_sum_256(v, red) * (1.0f / 256.0f);
    float d = v - m;
    float var = block_reduce_sum_256(d * d, red) * (1.0f / 256.0f);
    float inv = 1.f / sqrtf(var + 1e-5f);
    xln[(size_t)row * DIMn + tid] = d * inv * ln1_g[tid] + ln1_b[tid];
  }
}

// ---------------------------------------------------------------------------
// fp32 GEMM, 32x64 tile, BK=32, 2x4 microtile, register double-buffered.
// A2: A-stage sums two partials; aact==1: gelu after the sum.
// Dual-N (W2n at col>=N1), dual-K (k>=Ksplit reads Wkb), split-K via z.
// act: 0 none, 1 exact gelu, 4 qkv mode (rope cols<1024; k section -> kT).
__global__ __launch_bounds__(256) void gemm_kernel(
    const float* __restrict__ A, const float* __restrict__ A2, int aact,
    const float* __restrict__ W1, int N1, const float* __restrict__ b1,
    const float* __restrict__ W2n, int N2, const float* __restrict__ b2,
    const float* __restrict__ Wkb, int Ksplit, float* __restrict__ C, int M,
    int Ntot, int K, int kspan, int act, const float* __restrict__ cost,
    const float* __restrict__ sint, float* __restrict__ kT) {
  __shared__ float As[32][34];
  __shared__ __align__(16) float Bs[32][68];
  int tid = threadIdx.x;
  int bx = blockIdx.x, by = blockIdx.y, zid = blockIdx.z;
  int tx = tid & 15, ty = tid >> 4;
  int arow = tid >> 3, acol = (tid & 7) << 2;
  int brow = tid >> 4, bcol = (tid & 15) << 2;
  int col0 = bx * 64;
  const float* W = W1;
  const float* bias = b1;
  int Nw = N1, wcol = col0;
  if (W2n && col0 >= N1) {
    W = W2n;
    bias = b2;
    Nw = N2;
    wcol = col0 - N1;
  }
  int kb = zid * kspan, kend = kb + kspan;
  const float* arp = A + (size_t)(by * 32 + arow) * K;
  const float* arp2 = A2 ? A2 + (size_t)(by * 32 + arow) * K : nullptr;

  auto load_a = [&](int kpos) -> float4 {
    float4 a = *(const float4*)(arp + kpos + acol);
    if (arp2) {
      float4 a2 = *(const float4*)(arp2 + kpos + acol);
      a.x += a2.x;
      a.y += a2.y;
      a.z += a2.z;
      a.w += a2.w;
    }
    if (aact == 1) {
      a.x = gelu_exact(a.x);
      a.y = gelu_exact(a.y);
      a.z = gelu_exact(a.z);
      a.w = gelu_exact(a.w);
    }
    return a;
  };

  float4 a_nxt = load_a(kb);
  const float* w0p;
  const float* w1p;
  {
    int kr0 = kb + brow, kr1 = kb + brow + 16;
    w0p = (Ksplit && kr0 >= Ksplit)
              ? Wkb + (size_t)(kr0 - Ksplit) * Nw + wcol + bcol
              : W + (size_t)kr0 * Nw + wcol + bcol;
    w1p = (Ksplit && kr1 >= Ksplit)
              ? Wkb + (size_t)(kr1 - Ksplit) * Nw + wcol + bcol
              : W + (size_t)kr1 * Nw + wcol + bcol;
  }
  float4 b0_nxt = *(const float4*)w0p;
  float4 b1_nxt = *(const float4*)w1p;

  float acc[2][4] = {};
  for (int k0 = kb; k0 < kend; k0 += 32) {
    As[acol + 0][arow] = a_nxt.x;
    As[acol + 1][arow] = a_nxt.y;
    As[acol + 2][arow] = a_nxt.z;
    As[acol + 3][arow] = a_nxt.w;
    *(float4*)&Bs[brow][bcol] = b0_nxt;
    *(float4*)&Bs[brow + 16][bcol] = b1_nxt;
    __syncthreads();
    int kn = k0 + 32;
    if (kn < kend) {
      a_nxt = load_a(kn);
      int kr0 = kn + brow, kr1 = kn + brow + 16;
      w0p = (Ksplit && kr0 >= Ksplit)
                ? Wkb + (size_t)(kr0 - Ksplit) * Nw + wcol + bcol
                : W + (size_t)kr0 * Nw + wcol + bcol;
      w1p = (Ksplit && kr1 >= Ksplit)
                ? Wkb + (size_t)(kr1 - Ksplit) * Nw + wcol + bcol
                : W + (size_t)kr1 * Nw + wcol + bcol;
      b0_nxt = *(const float4*)w0p;
      b1_nxt = *(const float4*)w1p;
    }
#pragma unroll
    for (int kk = 0; kk < 32; ++kk) {
      float2 av = *(const float2*)&As[kk][ty * 2];
      float4 bv = *(const float4*)&Bs[kk][tx * 4];
      acc[0][0] += av.x * bv.x;
      acc[0][1] += av.x * bv.y;
      acc[0][2] += av.x * bv.z;
      acc[0][3] += av.x * bv.w;
      acc[1][0] += av.y * bv.x;
      acc[1][1] += av.y * bv.y;
      acc[1][2] += av.y * bv.z;
      acc[1][3] += av.y * bv.w;
    }
    __syncthreads();
  }
  int ccol = wcol + tx * 4;
  bool ksec = (act == 4) && (col0 >= 512) && (col0 < 1024);
  float* trans = (float*)Bs;
  float* Cz = C + (size_t)zid * M * Ntot;
#pragma unroll
  for (int u = 0; u < 2; ++u) {
    int r = by * 32 + ty * 2 + u;
    float o[4];
#pragma unroll
    for (int w = 0; w < 4; ++w)
      o[w] = acc[u][w] + (zid == 0 ? bias[ccol + w] : 0.f);
    if (act == 1) {
#pragma unroll
      for (int w = 0; w < 4; ++w) o[w] = gelu_exact(o[w]);
    } else if (act == 4 && col0 < 1024) {
      int n = r & 127;
      int p0 = (ccol & 63) >> 1;
      float c0 = cost[n * 32 + p0], s0 = sint[n * 32 + p0];
      float c1 = cost[n * 32 + p0 + 1], s1 = sint[n * 32 + p0 + 1];
      float x0 = o[0], x1 = o[1], x2 = o[2], x3 = o[3];
      o[0] = x0 * c0 - x1 * s0;
      o[1] = x1 * c0 + x0 * s0;
      o[2] = x2 * c1 - x3 * s1;
      o[3] = x3 * c1 + x2 * s1;
    }
    if (ksec) {
      int jl = ty * 2 + u;
#pragma unroll
      for (int w = 0; w < 4; ++w) trans[(tx * 4 + w) * 33 + jl] = o[w];
    } else {
      float4 o4 = {o[0], o[1], o[2], o[3]};
      *(float4*)(Cz + (size_t)r * Ntot + col0 + tx * 4) = o4;
    }
  }
  if (ksec) {
    __syncthreads();
    int h = (col0 - 512) >> 6;
    int bb = (by * 32) >> 7;
#pragma unroll
    for (int q = 0; q < 2; ++q) {
      int f4 = tid * 2 + q;
      int dl = f4 >> 3, j4 = (f4 & 7) << 2;
      int jj = (by * 32 + j4) & 127;
      float4 o4 = {trans[dl * 33 + j4], trans[dl * 33 + j4 + 1],
                   trans[dl * 33 + j4 + 2], trans[dl * 33 + j4 + 3]};
      *(float4*)(kT + ((size_t)(bb * 8 + h) * 64 + dl) * 128 + jj) = o4;
    }
  }
}

// ---------------------------------------------------------------------------
// Attention + qe + out-proj partial. Block per (b,h,i-quad), 128 threads.
// Writes per-head proj partial: proj[h*PART + row*256 + n].
__global__ __launch_bounds__(128) void attn_kernel(
    const float* __restrict__ qkv, const float* __restrict__ e,
    const float* __restrict__ eT, const float* __restrict__ kT,
    const float* __restrict__ wek, const float* __restrict__ w_out,
    const float* __restrict__ W2, float* __restrict__ proj) {
  __shared__ __align__(16) float qs[256];
  __shared__ __align__(16) float qes[256];
  __shared__ __align__(16) float att[512];
  __shared__ float avh[512];
  __shared__ float aeh[512];
  __shared__ float wekh[64 * 65];
  int blk = blockIdx.x;
  int iq = blk & 31;
  int bh = blk >> 5;
  int h = bh & 7, b = bh >> 3;
  int i0 = iq * 4;
  int row0 = b * 128 + i0;
  int tid = threadIdx.x;

  for (int f = tid; f < 256; f += 128) {
    int ii = f >> 6, d = f & 63;
    qs[f] = qkv[(size_t)(row0 + ii) * QKVW + h * 64 + d];
  }
  for (int f = tid; f < 4096; f += 128) {
    int c = f >> 6, d = f & 63;
    wekh[c * 65 + d] = wek[(size_t)c * INNERn + h * 64 + d];
  }
  __syncthreads();

  for (int f = tid; f < 256; f += 128) {
    int ii = f >> 6, c = f & 63;
    float acc = 0.f;
#pragma unroll
    for (int d = 0; d < 64; ++d) acc += qs[ii * 64 + d] * wekh[c * 65 + d];
    qes[f] = acc;
  }
  __syncthreads();

  int i2 = tid >> 5, j4 = tid & 31;
  float s0 = 0.f, s1 = 0.f, s2 = 0.f, s3 = 0.f;
  {
    const float* ktb = kT + ((size_t)bh * 64) * 128 + j4 * 4;
#pragma unroll
    for (int d4 = 0; d4 < 64; d4 += 4) {
      float4 q4 = *(const float4*)&qs[i2 * 64 + d4];
      float4 k0 = *(const float4*)(ktb + (size_t)(d4 + 0) * 128);
      float4 k1 = *(const float4*)(ktb + (size_t)(d4 + 1) * 128);
      float4 k2 = *(const float4*)(ktb + (size_t)(d4 + 2) * 128);
      float4 k3 = *(const float4*)(ktb + (size_t)(d4 + 3) * 128);
      s0 += q4.x * k0.x + q4.y * k1.x + q4.z * k2.x + q4.w * k3.x;
      s1 += q4.x * k0.y + q4.y * k1.y + q4.z * k2.y + q4.w * k3.y;
      s2 += q4.x * k0.z + q4.y * k1.z + q4.z * k2.z + q4.w * k3.z;
      s3 += q4.x * k0.w + q4.y * k1.w + q4.z * k2.w + q4.w * k3.w;
    }
    const float* eb = e + ((size_t)(row0 + i2) * 64) * 128 + j4 * 4;
#pragma unroll
    for (int c4 = 0; c4 < 64; c4 += 4) {
      float4 qe4 = *(const float4*)&qes[i2 * 64 + c4];
      float4 e0 = *(const float4*)(eb + (size_t)(c4 + 0) * 128);
      float4 e1 = *(const float4*)(eb + (size_t)(c4 + 1) * 128);
      float4 e2 = *(const float4*)(eb + (size_t)(c4 + 2) * 128);
      float4 e3 = *(const float4*)(eb + (size_t)(c4 + 3) * 128);
      s0 += qe4.x * e0.x + qe4.y * e1.x + qe4.z * e2.x + qe4.w * e3.x;
      s1 += qe4.x * e0.y + qe4.y * e1.y + qe4.z * e2.y + qe4.w * e3.y;
      s2 += qe4.x * e0.z + qe4.y * e1.z + qe4.z * e2.z + qe4.w * e3.z;
      s3 += qe4.x * e0.w + qe4.y * e1.w + qe4.z * e2.w + qe4.w * e3.w;
    }
    s0 *= 0.125f;
    s1 *= 0.125f;
    s2 *= 0.125f;
    s3 *= 0.125f;
  }
  {
    float mx = fmaxf(fmaxf(s0, s1), fmaxf(s2, s3));
#pragma unroll
    for (int m = 16; m >= 1; m >>= 1) mx = fmaxf(mx, __shfl_xor(mx, m));
    float p0 = expf(s0 - mx), p1 = expf(s1 - mx), p2 = expf(s2 - mx),
          p3 = expf(s3 - mx);
    float sm = p0 + p1 + p2 + p3;
#pragma unroll
    for (int m = 16; m >= 1; m >>= 1) sm += __shfl_xor(sm, m);
    float inv = 1.f / sm;
    float4 a4 = {p0 * inv, p1 * inv, p2 * inv, p3 * inv};
    *(float4*)&att[i2 * 128 + j4 * 4] = a4;
  }
  __syncthreads();

  {
    int d = tid & 63, half = tid >> 6;
    float av0 = 0.f, av1 = 0.f, av2 = 0.f, av3 = 0.f;
    float ae0 = 0.f, ae1 = 0.f, ae2 = 0.f, ae3 = 0.f;
    const float* vb = qkv + (size_t)(b * 128) * QKVW + 1024 + h * 64 + d;
    const float* etb = eT + ((size_t)row0 * 128) * 64 + d;
    for (int jq = 0; jq < 16; ++jq) {
      int jb = half * 64 + jq * 4;
      float4 a0 = *(const float4*)&att[0 * 128 + jb];
      float4 a1 = *(const float4*)&att[1 * 128 + jb];
      float4 a2 = *(const float4*)&att[2 * 128 + jb];
      float4 a3 = *(const float4*)&att[3 * 128 + jb];
#pragma unroll
      for (int t = 0; t < 4; ++t) {
        int j = jb + t;
        float vv = vb[(size_t)j * QKVW];
        float at0 = ((const float*)&a0)[t];
        float at1 = ((const float*)&a1)[t];
        float at2 = ((const float*)&a2)[t];
        float at3 = ((const float*)&a3)[t];
        av0 += at0 * vv;
        av1 += at1 * vv;
        av2 += at2 * vv;
        av3 += at3 * vv;
        float e0 = etb[(size_t)j * 64];
        float e1 = etb[8192 + (size_t)j * 64];
        float e2 = etb[16384 + (size_t)j * 64];
        float e3 = etb[24576 + (size_t)j * 64];
        ae0 += at0 * e0;
        ae1 += at1 * e1;
        ae2 += at2 * e2;
        ae3 += at3 * e3;
      }
    }
    avh[half * 256 + 0 * 64 + d] = av0;
    avh[half * 256 + 1 * 64 + d] = av1;
    avh[half * 256 + 2 * 64 + d] = av2;
    avh[half * 256 + 3 * 64 + d] = av3;
    aeh[half * 256 + 0 * 64 + d] = ae0;
    aeh[half * 256 + 1 * 64 + d] = ae1;
    aeh[half * 256 + 2 * 64 + d] = ae2;
    aeh[half * 256 + 3 * 64 + d] = ae3;
  }
  __syncthreads();

  for (int f = tid; f < 256; f += 128) {
    int ii = f >> 6, dd = f & 63;
    att[ii * 128 + dd] = avh[ii * 64 + dd] + avh[256 + ii * 64 + dd];
    att[ii * 128 + 64 + dd] = aeh[ii * 64 + dd] + aeh[256 + ii * 64 + dd];
  }
  __syncthreads();

  {
    int rp = tid >> 6, n4 = (tid & 63) << 2;
    int r0 = rp * 2, r1 = rp * 2 + 1;
    float o0[4] = {}, o1[4] = {};
    const float* wo = w_out + (size_t)(h * 64) * 256 + n4;
#pragma unroll 8
    for (int k = 0; k < 64; ++k) {
      float4 w4 = *(const float4*)(wo + (size_t)k * 256);
      float a0 = att[r0 * 128 + k];
      float a1 = att[r1 * 128 + k];
      o0[0] += a0 * w4.x;
      o0[1] += a0 * w4.y;
      o0[2] += a0 * w4.z;
      o0[3] += a0 * w4.w;
      o1[0] += a1 * w4.x;
      o1[1] += a1 * w4.y;
      o1[2] += a1 * w4.z;
      o1[3] += a1 * w4.w;
    }
    const float* w2 = W2 + (size_t)(h * 64) * 256 + n4;
#pragma unroll 8
    for (int k = 0; k < 64; ++k) {
      float4 w4 = *(const float4*)(w2 + (size_t)k * 256);
      float a0 = att[r0 * 128 + 64 + k];
      float a1 = att[r1 * 128 + 64 + k];
      o0[0] += a0 * w4.x;
      o0[1] += a0 * w4.y;
      o0[2] += a0 * w4.z;
      o0[3] += a0 * w4.w;
      o1[0] += a1 * w4.x;
      o1[1] += a1 * w4.y;
      o1[2] += a1 * w4.z;
      o1[3] += a1 * w4.w;
    }
    float* pp = proj + (size_t)h * PART;
    float4 v0 = {o0[0], o0[1], o0[2], o0[3]};
    float4 v1 = {o1[0], o1[1], o1[2], o1[3]};
    *(float4*)(pp + (size_t)(row0 + r0) * 256 + n4) = v0;
    *(float4*)(pp + (size_t)(row0 + r1) * 256 + n4) = v1;
  }
}

// ---------------------------------------------------------------------------
// Gated residual + optional fused LN. x = sum of nparts partials (+ badd).
__global__ __launch_bounds__(256) void gate_ln_kernel(
    const float* __restrict__ x, int nparts, const float* __restrict__ badd,
    float* __restrict__ nodes, const float* __restrict__ gw,
    const float* __restrict__ lng, const float* __restrict__ lnb,
    float* __restrict__ xln) {
  __shared__ float red[4];
  int row = blockIdx.x, tid = threadIdx.x;
  size_t off = (size_t)row * DIMn + tid;
  float xv = x[off];
  for (int p = 1; p < nparts; ++p) xv += x[off + (size_t)p * PART];
  if (badd) xv += badd[tid];
  float rv = nodes[off];
  float pv =
      xv * gw[tid] + rv * gw[DIMn + tid] + (xv - rv) * gw[2 * DIMn + tid];
  float ssum = block_reduce_sum_256(pv, red);
  float gsig = 1.f / (1.f + expf(-ssum));
  float nv = xv * gsig + rv * (1.f - gsig);
  nodes[off] = nv;
  if (lng) {
    float m = block_reduce_sum_256(nv, red) * (1.0f / 256.0f);
    float d = nv - m;
    float var = block_reduce_sum_256(d * d, red) * (1.0f / 256.0f);
    float inv = 1.f / sqrtf(var + 1e-5f);
    xln[off] = d * inv * lng[tid] + lnb[tid];
  }
}

// ---------------------------------------------------------------------------
// VQ nearest neighbor: thread-per-codebook-entry, 4 rows per block.
__global__ __launch_bounds__(256) void vq_kernel(
    const float* __restrict__ nodes, const float* __restrict__ codebook,
    float* __restrict__ out) {
  __shared__ __align__(16) float zs[4 * 256];
  __shared__ float wval[4][4];
  __shared__ int widx[4][4];
  __shared__ int fidx[4];
  int row0 = blockIdx.x * 4;
  int tid = threadIdx.x;
  for (int f = tid; f < 1024; f += 256) zs[f] = nodes[(size_t)row0 * DIMn + f];
  __syncthreads();
  int k1 = tid, k2 = tid + 256;
  const float4* c1p = (const float4*)(codebook + (size_t)k1 * DIMn);
  const float4* c2p = (const float4*)(codebook + (size_t)k2 * DIMn);
  float dot[4][2] = {};
  float cc0 = 0.f, cc1 = 0.f;
#pragma unroll 8
  for (int d4 = 0; d4 < 64; ++d4) {
    float4 c1 = c1p[d4], c2 = c2p[d4];
    cc0 += c1.x * c1.x + c1.y * c1.y + c1.z * c1.z + c1.w * c1.w;
    cc1 += c2.x * c2.x + c2.y * c2.y + c2.z * c2.z + c2.w * c2.w;
#pragma unroll
    for (int r = 0; r < 4; ++r) {
      float4 z = *(const float4*)&zs[r * 256 + d4 * 4];
      dot[r][0] += c1.x * z.x + c1.y * z.y + c1.z * z.z + c1.w * z.w;
      dot[r][1] += c2.x * z.x + c2.y * z.y + c2.z * z.z + c2.w * z.w;
    }
  }
  int lane = tid & 63, w = tid >> 6;
#pragma unroll
  for (int r = 0; r < 4; ++r) {
    float bv = cc0 - 2.f * dot[r][0];
    int bi = k1;
    float v2 = cc1 - 2.f * dot[r][1];
    if (v2 < bv) {
      bv = v2;
      bi = k2;
    }
#pragma unroll
    for (int m = 32; m >= 1; m >>= 1) {
      float ov = __shfl_xor(bv, m);
      int oi = __shfl_xor(bi, m);
      if (ov < bv || (ov == bv && oi < bi)) {
        bv = ov;
        bi = oi;
      }
    }
    if (lane == 0) {
      wval[r][w] = bv;
      widx[r][w] = bi;
    }
  }
  __syncthreads();
  if (tid < 4) {
    float bb = wval[tid][0];
    int bi = widx[tid][0];
    for (int t = 1; t < 4; ++t)
      if (wval[tid][t] < bb || (wval[tid][t] == bb && widx[tid][t] < bi)) {
        bb = wval[tid][t];
        bi = widx[tid][t];
      }
    fidx[tid] = bi;
  }
  __syncthreads();
  for (int f = tid; f < 1024; f += 256) {
    int r = f >> 8, d = f & 255;
    float zv = zs[f];
    float zq = codebook[(size_t)fidx[r] * DIMn + d];
    out[(size_t)(row0 + r) * DIMn + d] = zv + (zq - zv);
  }
}

// ---------------------------------------------------------------------------
extern "C" void kernel_launch(void* const* d_in, const int* in_sizes, int n_in,
                              void* d_out, int out_size, void* d_ws,
                              size_t ws_size, hipStream_t stream) {
  const float* nodes_in = (const float*)d_in[0];
  const float* edges = (const float*)d_in[1];
  const float* edge_ln_g = (const float*)d_in[2];
  const float* edge_ln_b = (const float*)d_in[3];
  const float* ln1_g = (const float*)d_in[4];
  const float* ln1_b = (const float*)d_in[5];
  const float* w_exp = (const float*)d_in[6];
  const float* b_exp = (const float*)d_in[7];
  const float* w_q = (const float*)d_in[8];
  const float* b_q = (const float*)d_in[9];
  const float* w_kv = (const float*)d_in[10];
  const float* b_kv = (const float*)d_in[11];
  const float* w_ekv = (const float*)d_in[12];
  const float* b_ekv = (const float*)d_in[13];
  const float* w_out = (const float*)d_in[14];
  const float* b_out = (const float*)d_in[15];
  const float* gate1_w = (const float*)d_in[16];
  const float* ln2_g = (const float*)d_in[17];
  const float* ln2_b = (const float*)d_in[18];
  const float* w_ff1 = (const float*)d_in[19];
  const float* b_ff1 = (const float*)d_in[20];
  const float* w_ff2 = (const float*)d_in[21];
  const float* b_ff2 = (const float*)d_in[22];
  const float* gate2_w = (const float*)d_in[23];
  const float* codebook = (const float*)d_in[24];

  float* ws = (float*)d_ws;
  float* e_buf = ws;                  // 4194304
  float* eT_buf = e_buf + 4194304;    // 4194304
  float* cost = eT_buf + 4194304;     // 4096
  float* sint = cost + 4096;          // 4096
  float* nodes = sint + 4096;         // 131072
  float* xln = nodes + 131072;        // 131072
  float* xe = xln + 131072;           // 524288 (2 split-K partials)
  float* qkvb = xe + 524288;          // 786432
  float* kTb = qkvb + 786432;         // 262144
  float* proj = kTb + 262144;         // 1048576 (8 per-head / 4 splitK parts)
  float* ff1 = proj + 1048576;        // 1048576 (2 split-K partials)
  float* W2buf = ff1 + 1048576;       // 262144
  float* bout2 = W2buf + 262144;      // 512

  // one-shot setup: wfold + edge LN + rope tables + LN0 (+nodes copy)
  prep_kernel<<<1112, 256, 0, stream>>>(
      edges, edge_ln_g, edge_ln_b, e_buf, eT_buf, cost, sint, nodes_in, ln1_g,
      ln1_b, xln, nodes, w_ekv, w_out, b_ekv, b_out, W2buf, bout2);

  for (int l = 0; l < DEPTHn; ++l) {
    // exp: split-K x2 -> xe partials
    gemm_kernel<<<dim3(8, 16, 2), 256, 0, stream>>>(
        xln, nullptr, 0, w_exp + l * 256 * 512, 512, b_exp + l * 512, nullptr,
        0, nullptr, nullptr, 0, xe, 512, 512, 256, 128, 0, cost, sint,
        nullptr);
    // fused q|kv (A = sum of 2 xe partials), rope epilogue + kT scatter
    gemm_kernel<<<dim3(24, 16, 1), 256, 0, stream>>>(
        xe, xe + 262144, 0, w_q + l * 512 * 512, 512, b_q + l * 512,
        w_kv + l * 512 * 1024, 1024, b_kv + l * 1024, nullptr, 0, qkvb, 512,
        QKVW, 512, 512, 4, cost, sint, kTb);
    // attention (+qe, +out-proj per-head partials)
    attn_kernel<<<1024, 128, 0, stream>>>(qkvb, e_buf, eT_buf, kTb,
                                          w_ekv + l * 64 * 512,
                                          w_out + l * 512 * 256,
                                          W2buf + l * 512 * 256, proj);
    gate_ln_kernel<<<512, 256, 0, stream>>>(
        proj, 8, bout2 + l * 256, nodes, gate1_w + l * 768, ln2_g + l * 256,
        ln2_b + l * 256, xln);
    // ff1: split-K x2 (gelu deferred to ff2 A-stage)
    gemm_kernel<<<dim3(16, 16, 2), 256, 0, stream>>>(
        xln, nullptr, 0, w_ff1 + l * 256 * 1024, 1024, b_ff1 + l * 1024,
        nullptr, 0, nullptr, nullptr, 0, ff1, 512, 1024, 256, 128, 0, cost,
        sint, nullptr);
    // ff2: A = gelu(ff1 p0 + p1), split-K x4 -> proj partials
    gemm_kernel<<<dim3(4, 16, 4), 256, 0, stream>>>(
        ff1, ff1 + 524288, 1, w_ff2 + l * 1024 * 256, 256, b_ff2 + l * 256,
        nullptr, 0, nullptr, nullptr, 0, proj, 512, 256, 1024, 256, 0, cost,
        sint, nullptr);
    const float* nlng = (l + 1 < DEPTHn) ? ln1_g + (l + 1) * 256 : nullptr;
    const float* nlnb = (l + 1 < DEPTHn) ? ln1_b + (l + 1) * 256 : nullptr;
    gate_ln_kernel<<<512, 256, 0, stream>>>(proj, 4, nullptr, nodes,
                                            gate2_w + l * 768, nlng, nlnb,
                                            xln);
  }
  vq_kernel<<<128, 256, 0, stream>>>(nodes, codebook, (float*)d_out);
}